// Round 6
// baseline (761.057 us; speedup 1.0000x reference)
//
#include <hip/hip_runtime.h>
#include <hip/hip_bf16.h>

// GCN forward on MI355X.
//   adjb = bf16(adj) zero-padded [KP][KP], SWIZZLED   (streaming cvt)
//   S1t  = (feat @ W1)^T   bf16 [HID][KP] swz         (gemm1: A=W1t, B=featb)
//   x1   = relu(adjb @ S1 + b1)  split-K=4 fp32 partials -> relu_bias_fin
//   S2t  = (x1 @ W2)^T     bf16 [CLS][KP] swz         (gemm3)
//   x2   = adjb @ S2       split-K=8 partials -> logsoftmax_fin
//
// R9: two structural fixes to the GEMM loop (R6/R8 showed bytes are NOT the
// bottleneck; execution is):
//  (1) LDS bank conflicts: As/Bs rows are 128B -> ds_read_b128 was a 16-way
//      conflict (lanes 0-15 same bank). Fix per guide G4/T2 + rule #21: all
//      bf16 ws buffers stored PRE-SWIZZLED (chunk c of row r at c^(r&7) within
//      each 64-col group); global_load_lds stays linear; compute reads XOR the
//      chunk index. Producers (cvt kernels, EPI0 epilogue, relu_bias_fin)
//      write swizzled.
//  (2) 1-phase -> 2-phase: double-buffered LDS, issue next tile's DMA BEFORE
//      computing current, ONE barrier per iter (T3-minimum recipe). DMA now
//      in flight during compute.
// R10/R11: resubmits (acquisition timeouts; never measured).

#define NROW 10000
#define FIN  512
#define HID  256
#define NCLS 64
#define KP   10048          // NROW rounded up to 64
#define KSPLIT2 4
#define KSPAN2  2560
#define KSPLIT4 8
#define KSPAN4  1280

typedef __bf16 bf8_t __attribute__((ext_vector_type(8)));
typedef __bf16 bf4_t __attribute__((ext_vector_type(4)));
typedef float  f4_t  __attribute__((ext_vector_type(4)));

typedef __attribute__((address_space(3))) void       lds_void;
typedef const __attribute__((address_space(1))) void glb_void;

__device__ __forceinline__ void dma16(const void* g, void* l) {
    __builtin_amdgcn_global_load_lds((glb_void*)g, (lds_void*)l, 16, 0, 0);
}

// swizzled column index: within each 64-col group, 8-elem chunk c -> c^(r&7)
__device__ __forceinline__ int swzc(int k, int r) {
    return (k & ~63) | ((((k >> 3) & 7) ^ (r & 7)) << 3) | (k & 7);
}

// ---------------- converts (all write SWIZZLED bf16) ----------------
// feat fp32 [NROW][FIN] -> featb [NROW][FIN] swz. LDW must be pow2 multiple of 64.
template<int LDW>
__global__ void cvt_f32_bf16_swz(const float* __restrict__ in, __bf16* __restrict__ out, int n) {
    int stride = gridDim.x * blockDim.x * 4;
    for (int i = (blockIdx.x * blockDim.x + threadIdx.x) * 4; i < n; i += stride) {
        f4_t v = *(const f4_t*)(in + i);
        bf4_t o;
        o[0] = (__bf16)v[0]; o[1] = (__bf16)v[1]; o[2] = (__bf16)v[2]; o[3] = (__bf16)v[3];
        int row = i / LDW, k = i & (LDW - 1);
        *(bf4_t*)(out + (long)row * LDW + swzc(k, row)) = o;
    }
}

// adj fp32 [NROW][NROW] -> adjb bf16 [KP][KP], zero-padded, swizzled.
__global__ void cvt_adj_bf16(const float* __restrict__ adj, __bf16* __restrict__ adjb) {
    const int r = blockIdx.x;
    const float* src = adj + (long)r * NROW;
    __bf16* dst = adjb + (long)r * KP;
    for (int ch = threadIdx.x; ch < KP / 8; ch += 256) {
        bf8_t o;
        if (r < NROW && ch < NROW / 8) {
            f4_t a = *(const f4_t*)(src + ch * 8);
            f4_t b = *(const f4_t*)(src + ch * 8 + 4);
            o[0] = (__bf16)a[0]; o[1] = (__bf16)a[1]; o[2] = (__bf16)a[2]; o[3] = (__bf16)a[3];
            o[4] = (__bf16)b[0]; o[5] = (__bf16)b[1]; o[6] = (__bf16)b[2]; o[7] = (__bf16)b[3];
        } else {
            o = bf8_t{(__bf16)0.f, (__bf16)0.f, (__bf16)0.f, (__bf16)0.f,
                      (__bf16)0.f, (__bf16)0.f, (__bf16)0.f, (__bf16)0.f};
        }
        int swch = (ch & ~7) | ((ch & 7) ^ (r & 7));
        *(bf8_t*)(dst + swch * 8) = o;
    }
}

// in [K][Nn] fp32 row-major -> out [Nn][K] bf16 swizzled (weights only; tiny)
__global__ void cvt_transpose(const float* __restrict__ in, __bf16* __restrict__ out, int K, int Nn) {
    int idx = blockIdx.x * 256 + threadIdx.x;
    if (idx < K * Nn) {
        int k = idx / Nn, n = idx % Nn;
        out[(long)n * K + swzc(k, n)] = (__bf16)in[idx];
    }
}

// ---------------- GEMM: D[M][Nn] = A[M][K] * Bt[Nn][K]^T ----------------
// BM = 64. A and B bf16, PRE-SWIZZLED storage, staged via global_load_lds.
// Double-buffered LDS, 2-phase pipeline, one barrier per K-iter.
// A rows allocated up to gridDim.x*BM; Bt rows up to gridDim.y*BN; K-extent
// of both >= kend (pads zero where they multiply real data).
// EPI 0: store bf16 SWIZZLED row-major to outB (ldo); EPI 2: fp32 partial.
template<int BN, int EPI>
__global__ void __launch_bounds__(256, (BN >= 128) ? 3 : 4)
gemm_bt(const __bf16* __restrict__ Ab, const __bf16* __restrict__ Bt,
        int M, int Nn, int K, int lda, int ldb, int kspan,
        float* __restrict__ outF, __bf16* __restrict__ outB,
        int ldo, long partStride)
{
    constexpr int BM = 64, BK = 64;
    constexpr int WM = BM / 2, WN = BN / 2;      // 2x2 waves
    constexpr int MI = WM / 16, NI = WN / 16;
    constexpr int ACALLS = BM / 32;              // 1KB DMA chunks per wave
    constexpr int BCALLS = BN / 32;
    constexpr int ASZ = BM * BK, BSZ = BN * BK;
    __shared__ __bf16 As[2 * ASZ];
    __shared__ __bf16 Bs[2 * BSZ];

    const int tid  = threadIdx.x;
    const int lane = tid & 63;
    const int wave = tid >> 6;
    const int wm = wave >> 1, wn = wave & 1;
    const int m0 = blockIdx.x * BM;
    const int n0 = blockIdx.y * BN;
    const int kbase = blockIdx.z * kspan;
    const int kend  = min(K, kbase + kspan);     // multiple of BK

    f4_t acc[MI][NI];
    #pragma unroll
    for (int i = 0; i < MI; i++)
        #pragma unroll
        for (int j = 0; j < NI; j++)
            acc[i][j] = f4_t{0.f, 0.f, 0.f, 0.f};

    const int lrow  = lane & 15;
    const int koff0 = (lane >> 4) * 8;
    const int l7    = lrow & 7;                  // == fragment row & 7

    // ---- hoisted staging pointers: chunk c = wave + j*4 covers rows [c*8,c*8+8)
    const __bf16* Arow[ACALLS];
    #pragma unroll
    for (int j = 0; j < ACALLS; ++j) {
        int c = wave + j * 4;
        Arow[j] = Ab + (long)(m0 + c * 8 + (lane >> 3)) * lda + (lane & 7) * 8;
    }
    const __bf16* Brow[BCALLS];
    #pragma unroll
    for (int j = 0; j < BCALLS; ++j) {
        int c = wave + j * 4;
        Brow[j] = Bt + (long)(n0 + c * 8 + (lane >> 3)) * ldb + (lane & 7) * 8;
    }

    // ---- 2-phase pipelined K-loop, one barrier per iter ----
    int cur = 0;
    {   // prologue: stage tile 0
        #pragma unroll
        for (int j = 0; j < ACALLS; ++j)
            dma16(Arow[j] + kbase, &As[(wave + j * 4) * 512]);
        #pragma unroll
        for (int j = 0; j < BCALLS; ++j)
            dma16(Brow[j] + kbase, &Bs[(wave + j * 4) * 512]);
    }
    __syncthreads();

    for (int k0 = kbase; k0 < kend; k0 += BK) {
        // issue next tile's DMA into the other buffer (overlaps with compute)
        if (k0 + BK < kend) {
            int nxt = cur ^ 1;
            #pragma unroll
            for (int j = 0; j < ACALLS; ++j)
                dma16(Arow[j] + (k0 + BK), &As[nxt * ASZ + (wave + j * 4) * 512]);
            #pragma unroll
            for (int j = 0; j < BCALLS; ++j)
                dma16(Brow[j] + (k0 + BK), &Bs[nxt * BSZ + (wave + j * 4) * 512]);
        }

        // compute on current buffer; swizzled chunk reads (conflict-free)
        #pragma unroll
        for (int ks = 0; ks < BK; ks += 32) {
            const int cc = (ks + koff0) >> 3;          // original chunk idx
            const int co = ((cc ^ l7) << 3);           // swizzled byte-chunk off
            bf8_t af[MI], bfv[NI];
            #pragma unroll
            for (int mi = 0; mi < MI; mi++)
                af[mi] = *(const bf8_t*)&As[cur * ASZ + (wm * WM + mi * 16 + lrow) * BK + co];
            #pragma unroll
            for (int ni = 0; ni < NI; ni++)
                bfv[ni] = *(const bf8_t*)&Bs[cur * BSZ + (wn * WN + ni * 16 + lrow) * BK + co];
            #pragma unroll
            for (int mi = 0; mi < MI; mi++)
                #pragma unroll
                for (int ni = 0; ni < NI; ni++)
                    acc[mi][ni] = __builtin_amdgcn_mfma_f32_16x16x32_bf16(
                        af[mi], bfv[ni], acc[mi][ni], 0, 0, 0);
        }
        __syncthreads();   // drains next-tile DMA (vmcnt 0) + all ds_reads
        cur ^= 1;
    }

    // ---- epilogue ----  C/D layout: col = lane&15, row = (lane>>4)*4 + reg
    const int erow = wm * WM + (lane >> 4) * 4;
    const int ecol = wn * WN + lrow;
    #pragma unroll
    for (int mi = 0; mi < MI; mi++) {
        #pragma unroll
        for (int ni = 0; ni < NI; ni++) {
            #pragma unroll
            for (int r = 0; r < 4; r++) {
                int grow = m0 + erow + mi * 16 + r;
                int gcol = n0 + ecol + ni * 16;
                if (grow < M && gcol < Nn) {
                    float v = acc[mi][ni][r];
                    if constexpr (EPI == 0) {
                        outB[(long)grow * ldo + swzc(gcol, grow)] = (__bf16)v;
                    } else {
                        outF[blockIdx.z * partStride + (long)grow * ldo + gcol] = v;
                    }
                }
            }
        }
    }
}

// ---------------- GEMM2 reduce: x1 = relu(sum(part) + b1) ----------------
// outF (d_out) linear fp32; x1b bf16 SWIZZLED [row][HID].
__global__ void relu_bias_fin(const float* __restrict__ part, const float* __restrict__ b1,
                              float* __restrict__ outF, __bf16* __restrict__ outB) {
    long i = (long)(blockIdx.x * 256 + threadIdx.x) * 4;
    f4_t v = *(const f4_t*)(part + i);
    #pragma unroll
    for (int s = 1; s < KSPLIT2; s++) {
        f4_t p = *(const f4_t*)(part + (long)s * NROW * HID + i);
        v[0] += p[0]; v[1] += p[1]; v[2] += p[2]; v[3] += p[3];
    }
    int row = (int)(i >> 8);          // HID = 256
    int col = (int)(i & (HID - 1));
    f4_t b = *(const f4_t*)(b1 + col);
    f4_t y;
    bf4_t yb;
    #pragma unroll
    for (int j = 0; j < 4; j++) {
        y[j] = fmaxf(v[j] + b[j], 0.f);
        yb[j] = (__bf16)y[j];
    }
    *(f4_t*)(outF + i) = y;
    *(bf4_t*)(outB + (long)row * HID + swzc(col, row)) = yb;
}

// ---------------- split-K reduce + bias + log_softmax ----------------
__global__ void logsoftmax_fin(const float* __restrict__ part, const float* __restrict__ b2,
                               float* __restrict__ out, int M) {
    int row  = blockIdx.x * 4 + (threadIdx.x >> 6);
    int lane = threadIdx.x & 63;
    if (row >= M) return;
    float v = b2[lane];
    #pragma unroll
    for (int s = 0; s < KSPLIT4; s++) v += part[((long)s * M + row) * NCLS + lane];
    float m = v;
    #pragma unroll
    for (int off = 32; off > 0; off >>= 1) m = fmaxf(m, __shfl_xor(m, off));
    float e = __expf(v - m);
    float sum = e;
    #pragma unroll
    for (int off = 32; off > 0; off >>= 1) sum += __shfl_xor(sum, off);
    out[(long)row * NCLS + lane] = (v - m) - __logf(sum);
}

extern "C" void kernel_launch(void* const* d_in, const int* in_sizes, int n_in,
                              void* d_out, int out_size, void* d_ws, size_t ws_size,
                              hipStream_t stream) {
    const float* feat = (const float*)d_in[0];
    const float* adj  = (const float*)d_in[1];
    const float* W1   = (const float*)d_in[2];
    const float* b1   = (const float*)d_in[3];
    const float* W2   = (const float*)d_in[4];
    const float* b2   = (const float*)d_in[5];
    float* out = (float*)d_out;
    char* ws = (char*)d_ws;

    // workspace layout (256B aligned) -- ~265 MB total (all bf16 bufs swizzled)
    __bf16* featb = (__bf16*)(ws);                    // [10048][FIN]  10,289,152
    __bf16* W1t   = (__bf16*)(ws + 10289152);         // [HID][FIN]       262,144
    __bf16* W2t   = (__bf16*)(ws + 10551296);         // [CLS][HID]        32,768
    __bf16* S1t   = (__bf16*)(ws + 10584064);         // [HID][KP]      5,144,576
    __bf16* x1b   = (__bf16*)(ws + 15728640);         // [10048][HID]   5,144,576
    __bf16* S2t   = (__bf16*)(ws + 20873216);         // [CLS][KP]      1,286,144
    float*  part  = (float*) (ws + 22159360);         // [4][N][HID] fp32 40,960,000
    __bf16* adjb  = (__bf16*)(ws + 63119360);         // [KP][KP]     201,928,704

    // Pad-K cols of S1t/S2t must be zero (S1t/S2t pads multiply adjb real
    // values -> must be 0; adjb pads are zeroed by cvt_adj_bf16).
    hipMemsetAsync(S1t, 0, (size_t)HID * KP * 2, stream);
    hipMemsetAsync(S2t, 0, (size_t)NCLS * KP * 2, stream);

    cvt_f32_bf16_swz<FIN><<<640, 256, 0, stream>>>(feat, featb, NROW * FIN);
    cvt_adj_bf16<<<KP, 256, 0, stream>>>(adj, adjb);
    cvt_transpose<<<(FIN * HID + 255) / 256, 256, 0, stream>>>(W1, W1t, FIN, HID);
    cvt_transpose<<<(HID * NCLS + 255) / 256, 256, 0, stream>>>(W2, W2t, HID, NCLS);

    // S1t[HID][n] = W1t @ featb^T   (M=256, Nn=NROW, K=FIN)
    gemm_bt<64, 0><<<dim3(4, 157, 1), 256, 0, stream>>>(
        W1t, featb, HID, NROW, FIN, FIN, FIN, FIN,
        nullptr, S1t, KP, 0);

    // x1 partials = adjb @ S1   (M=NROW, Nn=HID, K=KP, split-K=4)
    gemm_bt<128, 2><<<dim3(157, 2, KSPLIT2), 256, 0, stream>>>(
        adjb, S1t, NROW, HID, KP, KP, KP, KSPAN2,
        part, nullptr, HID, (long)NROW * HID);

    // x1 = relu(sum + b1) -> out fp32, x1b bf16 swz
    relu_bias_fin<<<NROW * HID / 4 / 256, 256, 0, stream>>>(part, b1, out, x1b);

    // S2t[CLS][n] = W2t @ x1b^T  (M=64, Nn=NROW, K=HID)
    gemm_bt<64, 0><<<dim3(1, 157, 1), 256, 0, stream>>>(
        W2t, x1b, NCLS, NROW, HID, HID, HID, HID,
        nullptr, S2t, KP, 0);

    // x2 partials = adjb @ S2   (M=NROW, Nn=NCLS, K=KP, split-K=8)
    gemm_bt<64, 2><<<dim3(157, 1, KSPLIT4), 256, 0, stream>>>(
        adjb, S2t, NROW, NCLS, KP, KP, KP, KSPAN4,
        part, nullptr, NCLS, (long)NROW * NCLS);

    // reduce + b2 + log_softmax -> second output
    logsoftmax_fin<<<2500, 256, 0, stream>>>(part, b2, out + (long)NROW * HID, NROW);
}

// Round 7
// 737.540 us; speedup vs baseline: 1.0319x; 1.0319x over previous
//
#include <hip/hip_runtime.h>
#include <hip/hip_bf16.h>

// GCN forward on MI355X.
//   S1t  = (feat @ W1)^T   bf16 [HID][KP] swz       (gemm1: A=W1t, B=featb, DMA)
//   x1   = relu(adj @ S1 + b1)  split-K=4 fp32 partials -> relu_bias_fin
//   S2t  = (x1 @ W2)^T     bf16 [CLS][KP] swz       (gemm3, DMA)
//   x2   = adj @ S2        split-K=8 partials -> logsoftmax_fin
//
// History: R6 (BN256, adj-once) neutral; R8 (adjb bf16 cvt + all-DMA) neutral
// (760); R9 (LDS swizzle + 2-phase dbuf) neutral (761). => none of those was
// the dominant term. Floor model says our kernels ~300us; either ~490us of
// harness poison fill is inside the timed region, or the adj GEMMs hide an
// unmodeled cost.
// R12: delete cvt_adj entirely (-100us of real work under either hypothesis).
// adj read fp32 DIRECTLY in GEMM2/GEMM4 via reg-staging that writes SWIZZLED
// LDS (ds_write can scatter; rule #21 only binds global_load_lds), inside the
// R9 2-phase double-buffered loop: issue A f4-loads + B dma16 for tile k+1
// BEFORE compute(k), cvt+ds_write AFTER (T14 load-early/write-late), one
// barrier per iter. B path stays pre-swizzled bf16 + global_load_lds.
// Clamped A addresses (row->M-1, col->Kclamp-4) are safe: clamped cols
// multiply memset-zero pad-K rows of S1t/S2t; clamped rows only feed
// guard-discarded outputs.

#define NROW 10000
#define FIN  512
#define HID  256
#define NCLS 64
#define KP   10048          // NROW rounded up to 64
#define KSPLIT2 4
#define KSPAN2  2560
#define KSPLIT4 8
#define KSPAN4  1280

typedef __bf16 bf8_t __attribute__((ext_vector_type(8)));
typedef __bf16 bf4_t __attribute__((ext_vector_type(4)));
typedef float  f4_t  __attribute__((ext_vector_type(4)));

typedef __attribute__((address_space(3))) void       lds_void;
typedef const __attribute__((address_space(1))) void glb_void;

__device__ __forceinline__ void dma16(const void* g, void* l) {
    __builtin_amdgcn_global_load_lds((glb_void*)g, (lds_void*)l, 16, 0, 0);
}

// swizzled column index: within each 64-col group, 8-elem chunk c -> c^(r&7)
__device__ __forceinline__ int swzc(int k, int r) {
    return (k & ~63) | ((((k >> 3) & 7) ^ (r & 7)) << 3) | (k & 7);
}

// ---------------- converts (write SWIZZLED bf16) ----------------
// feat fp32 [NROW][FIN] -> featb [NROW][FIN] swz. LDW pow2 multiple of 64.
template<int LDW>
__global__ void cvt_f32_bf16_swz(const float* __restrict__ in, __bf16* __restrict__ out, int n) {
    int stride = gridDim.x * blockDim.x * 4;
    for (int i = (blockIdx.x * blockDim.x + threadIdx.x) * 4; i < n; i += stride) {
        f4_t v = *(const f4_t*)(in + i);
        bf4_t o;
        o[0] = (__bf16)v[0]; o[1] = (__bf16)v[1]; o[2] = (__bf16)v[2]; o[3] = (__bf16)v[3];
        int row = i / LDW, k = i & (LDW - 1);
        *(bf4_t*)(out + (long)row * LDW + swzc(k, row)) = o;
    }
}

// in [K][Nn] fp32 row-major -> out [Nn][K] bf16 swizzled (weights only; tiny)
__global__ void cvt_transpose(const float* __restrict__ in, __bf16* __restrict__ out, int K, int Nn) {
    int idx = blockIdx.x * 256 + threadIdx.x;
    if (idx < K * Nn) {
        int k = idx / Nn, n = idx % Nn;
        out[(long)n * K + swzc(k, n)] = (__bf16)in[idx];
    }
}

// ---------------- GEMM: D[M][Nn] = A[M][K] * Bt[Nn][K]^T ----------------
// BM = 64. B bf16 PRE-SWIZZLED, staged via global_load_lds.
// A: AF32=false -> bf16 pre-swizzled DMA; AF32=true -> fp32 reg-staged with
// cvt + swizzled ds_write (clamped addresses; B pad-K must be zero).
// Double-buffered LDS, 2-phase pipeline, one barrier per K-iter.
// EPI 0: store bf16 SWIZZLED row-major to outB (ldo); EPI 2: fp32 partial.
template<int BN, bool AF32, int EPI>
__global__ void __launch_bounds__(256, (BN >= 128) ? 3 : 4)
gemm_bt(const void* __restrict__ Ap, const __bf16* __restrict__ Bt,
        int M, int Nn, int K, int Kclamp, int lda, int ldb, int kspan,
        float* __restrict__ outF, __bf16* __restrict__ outB,
        int ldo, long partStride)
{
    constexpr int BM = 64, BK = 64;
    constexpr int WM = BM / 2, WN = BN / 2;      // 2x2 waves
    constexpr int MI = WM / 16, NI = WN / 16;
    constexpr int ACALLS = BM / 32;              // 1KB DMA chunks per wave
    constexpr int BCALLS = BN / 32;
    constexpr int ASZ = BM * BK, BSZ = BN * BK;
    __shared__ __bf16 As[2 * ASZ];
    __shared__ __bf16 Bs[2 * BSZ];

    const int tid  = threadIdx.x;
    const int lane = tid & 63;
    const int wave = tid >> 6;
    const int wm = wave >> 1, wn = wave & 1;
    const int m0 = blockIdx.x * BM;
    const int n0 = blockIdx.y * BN;
    const int kbase = blockIdx.z * kspan;
    const int kend  = min(K, kbase + kspan);     // multiple of BK

    f4_t acc[MI][NI];
    #pragma unroll
    for (int i = 0; i < MI; i++)
        #pragma unroll
        for (int j = 0; j < NI; j++)
            acc[i][j] = f4_t{0.f, 0.f, 0.f, 0.f};

    const int lrow  = lane & 15;
    const int koff0 = (lane >> 4) * 8;
    const int l7    = lrow & 7;                  // == fragment row & 7

    // ---- hoisted staging pointers ----
    const __bf16* Brow[BCALLS];
    #pragma unroll
    for (int j = 0; j < BCALLS; ++j) {
        int c = wave + j * 4;
        Brow[j] = Bt + (long)(n0 + c * 8 + (lane >> 3)) * ldb + (lane & 7) * 8;
    }
    const __bf16* ArowB[ACALLS];
    const float*  ArowF[4];
    int Acol[4], AldsOff[4];
    if constexpr (AF32) {
        // 4 fp32 chunks/thread; row & col clamped (B pad-K zero => harmless).
        // swizzled LDS offset: logical 8-chunk (c4>>1) XOR (r&7), half (c4&1).
        #pragma unroll
        for (int i = 0; i < 4; ++i) {
            int idx = tid + i * 256;
            int r = idx >> 4, c4 = idx & 15;
            ArowF[i] = (const float*)Ap + (long)min(m0 + r, M - 1) * lda;
            Acol[i] = c4 * 4;
            AldsOff[i] = r * BK + ((((c4 >> 1) ^ (r & 7)) << 3) | ((c4 & 1) * 4));
        }
    } else {
        #pragma unroll
        for (int j = 0; j < ACALLS; ++j) {
            int c = wave + j * 4;
            ArowB[j] = (const __bf16*)Ap + (long)(m0 + c * 8 + (lane >> 3)) * lda + (lane & 7) * 8;
        }
    }

    // ---- prologue: stage tile kbase into buf 0 ----
    if constexpr (AF32) {
        f4_t av[4];
        #pragma unroll
        for (int i = 0; i < 4; ++i)
            av[i] = *(const f4_t*)(ArowF[i] + min(kbase + Acol[i], Kclamp - 4));
        #pragma unroll
        for (int i = 0; i < 4; ++i) {
            bf4_t o;
            o[0] = (__bf16)av[i][0]; o[1] = (__bf16)av[i][1];
            o[2] = (__bf16)av[i][2]; o[3] = (__bf16)av[i][3];
            *(bf4_t*)&As[AldsOff[i]] = o;
        }
    } else {
        #pragma unroll
        for (int j = 0; j < ACALLS; ++j)
            dma16(ArowB[j] + kbase, &As[(wave + j * 4) * 512]);
    }
    #pragma unroll
    for (int j = 0; j < BCALLS; ++j)
        dma16(Brow[j] + kbase, &Bs[(wave + j * 4) * 512]);
    __syncthreads();

    // ---- 2-phase pipelined K-loop, one barrier per iter ----
    int cur = 0;
    for (int k0 = kbase; k0 < kend; k0 += BK) {
        const bool has_next = (k0 + BK < kend);
        const int nxt = cur ^ 1;
        f4_t av[4];
        // issue next tile's loads BEFORE compute (latency hides under MFMA)
        if (has_next) {
            if constexpr (AF32) {
                #pragma unroll
                for (int i = 0; i < 4; ++i)
                    av[i] = *(const f4_t*)(ArowF[i] + min(k0 + BK + Acol[i], Kclamp - 4));
            } else {
                #pragma unroll
                for (int j = 0; j < ACALLS; ++j)
                    dma16(ArowB[j] + (k0 + BK), &As[nxt * ASZ + (wave + j * 4) * 512]);
            }
            #pragma unroll
            for (int j = 0; j < BCALLS; ++j)
                dma16(Brow[j] + (k0 + BK), &Bs[nxt * BSZ + (wave + j * 4) * 512]);
        }

        // compute on current buffer; swizzled chunk reads (conflict-free)
        #pragma unroll
        for (int ks = 0; ks < BK; ks += 32) {
            const int cc = (ks + koff0) >> 3;          // original chunk idx
            const int co = ((cc ^ l7) << 3);           // swizzled byte-chunk off
            bf8_t af[MI], bfv[NI];
            #pragma unroll
            for (int mi = 0; mi < MI; mi++)
                af[mi] = *(const bf8_t*)&As[cur * ASZ + (wm * WM + mi * 16 + lrow) * BK + co];
            #pragma unroll
            for (int ni = 0; ni < NI; ni++)
                bfv[ni] = *(const bf8_t*)&Bs[cur * BSZ + (wn * WN + ni * 16 + lrow) * BK + co];
            #pragma unroll
            for (int mi = 0; mi < MI; mi++)
                #pragma unroll
                for (int ni = 0; ni < NI; ni++)
                    acc[mi][ni] = __builtin_amdgcn_mfma_f32_16x16x32_bf16(
                        af[mi], bfv[ni], acc[mi][ni], 0, 0, 0);
        }

        // write-late: A(k+1) cvt + swizzled ds_write into nxt (after compute)
        if (has_next) {
            if constexpr (AF32) {
                #pragma unroll
                for (int i = 0; i < 4; ++i) {
                    bf4_t o;
                    o[0] = (__bf16)av[i][0]; o[1] = (__bf16)av[i][1];
                    o[2] = (__bf16)av[i][2]; o[3] = (__bf16)av[i][3];
                    *(bf4_t*)&As[nxt * ASZ + AldsOff[i]] = o;
                }
            }
        }
        __syncthreads();   // drains DMA (vmcnt0) + ds_writes for nxt
        cur ^= 1;
    }

    // ---- epilogue ----  C/D layout: col = lane&15, row = (lane>>4)*4 + reg
    const int erow = wm * WM + (lane >> 4) * 4;
    const int ecol = wn * WN + lrow;
    #pragma unroll
    for (int mi = 0; mi < MI; mi++) {
        #pragma unroll
        for (int ni = 0; ni < NI; ni++) {
            #pragma unroll
            for (int r = 0; r < 4; r++) {
                int grow = m0 + erow + mi * 16 + r;
                int gcol = n0 + ecol + ni * 16;
                if (grow < M && gcol < Nn) {
                    float v = acc[mi][ni][r];
                    if constexpr (EPI == 0) {
                        outB[(long)grow * ldo + swzc(gcol, grow)] = (__bf16)v;
                    } else {
                        outF[blockIdx.z * partStride + (long)grow * ldo + gcol] = v;
                    }
                }
            }
        }
    }
}

// ---------------- GEMM2 reduce: x1 = relu(sum(part) + b1) ----------------
// outF (d_out) linear fp32; x1b bf16 SWIZZLED [row][HID].
__global__ void relu_bias_fin(const float* __restrict__ part, const float* __restrict__ b1,
                              float* __restrict__ outF, __bf16* __restrict__ outB) {
    long i = (long)(blockIdx.x * 256 + threadIdx.x) * 4;
    f4_t v = *(const f4_t*)(part + i);
    #pragma unroll
    for (int s = 1; s < KSPLIT2; s++) {
        f4_t p = *(const f4_t*)(part + (long)s * NROW * HID + i);
        v[0] += p[0]; v[1] += p[1]; v[2] += p[2]; v[3] += p[3];
    }
    int row = (int)(i >> 8);          // HID = 256
    int col = (int)(i & (HID - 1));
    f4_t b = *(const f4_t*)(b1 + col);
    f4_t y;
    bf4_t yb;
    #pragma unroll
    for (int j = 0; j < 4; j++) {
        y[j] = fmaxf(v[j] + b[j], 0.f);
        yb[j] = (__bf16)y[j];
    }
    *(f4_t*)(outF + i) = y;
    *(bf4_t*)(outB + (long)row * HID + swzc(col, row)) = yb;
}

// ---------------- split-K reduce + bias + log_softmax ----------------
__global__ void logsoftmax_fin(const float* __restrict__ part, const float* __restrict__ b2,
                               float* __restrict__ out, int M) {
    int row  = blockIdx.x * 4 + (threadIdx.x >> 6);
    int lane = threadIdx.x & 63;
    if (row >= M) return;
    float v = b2[lane];
    #pragma unroll
    for (int s = 0; s < KSPLIT4; s++) v += part[((long)s * M + row) * NCLS + lane];
    float m = v;
    #pragma unroll
    for (int off = 32; off > 0; off >>= 1) m = fmaxf(m, __shfl_xor(m, off));
    float e = __expf(v - m);
    float sum = e;
    #pragma unroll
    for (int off = 32; off > 0; off >>= 1) sum += __shfl_xor(sum, off);
    out[(long)row * NCLS + lane] = (v - m) - __logf(sum);
}

extern "C" void kernel_launch(void* const* d_in, const int* in_sizes, int n_in,
                              void* d_out, int out_size, void* d_ws, size_t ws_size,
                              hipStream_t stream) {
    const float* feat = (const float*)d_in[0];
    const float* adj  = (const float*)d_in[1];
    const float* W1   = (const float*)d_in[2];
    const float* b1   = (const float*)d_in[3];
    const float* W2   = (const float*)d_in[4];
    const float* b2   = (const float*)d_in[5];
    float* out = (float*)d_out;
    char* ws = (char*)d_ws;

    // workspace layout (256B aligned) -- ~63 MB (all bf16 bufs swizzled)
    __bf16* featb = (__bf16*)(ws);                    // [10048][FIN]  10,289,152
    __bf16* W1t   = (__bf16*)(ws + 10289152);         // [HID][FIN]       262,144
    __bf16* W2t   = (__bf16*)(ws + 10551296);         // [CLS][HID]        32,768
    __bf16* S1t   = (__bf16*)(ws + 10584064);         // [HID][KP]      5,144,576
    __bf16* x1b   = (__bf16*)(ws + 15728640);         // [10048][HID]   5,144,576
    __bf16* S2t   = (__bf16*)(ws + 20873216);         // [CLS][KP]      1,286,144
    float*  part  = (float*) (ws + 22159360);         // [4][N][HID] fp32 40,960,000

    // Pad-K cols of S1t/S2t must be zero (clamped adj cols multiply them).
    hipMemsetAsync(S1t, 0, (size_t)HID * KP * 2, stream);
    hipMemsetAsync(S2t, 0, (size_t)NCLS * KP * 2, stream);

    cvt_f32_bf16_swz<FIN><<<640, 256, 0, stream>>>(feat, featb, NROW * FIN);
    cvt_transpose<<<(FIN * HID + 255) / 256, 256, 0, stream>>>(W1, W1t, FIN, HID);
    cvt_transpose<<<(HID * NCLS + 255) / 256, 256, 0, stream>>>(W2, W2t, HID, NCLS);

    // S1t[HID][n] = W1t @ featb^T   (M=256, Nn=NROW, K=FIN)
    gemm_bt<64, false, 0><<<dim3(4, 157, 1), 256, 0, stream>>>(
        W1t, featb, HID, NROW, FIN, FIN, FIN, FIN, FIN,
        nullptr, S1t, KP, 0);

    // x1 partials = adj @ S1   (M=NROW, Nn=HID, K=KP, split-K=4, fp32-A)
    gemm_bt<128, true, 2><<<dim3(157, 2, KSPLIT2), 256, 0, stream>>>(
        adj, S1t, NROW, HID, KP, NROW, NROW, KP, KSPAN2,
        part, nullptr, HID, (long)NROW * HID);

    // x1 = relu(sum + b1) -> out fp32, x1b bf16 swz
    relu_bias_fin<<<NROW * HID / 4 / 256, 256, 0, stream>>>(part, b1, out, x1b);

    // S2t[CLS][n] = W2t @ x1b^T  (M=64, Nn=NROW, K=HID)
    gemm_bt<64, false, 0><<<dim3(1, 157, 1), 256, 0, stream>>>(
        W2t, x1b, NCLS, NROW, HID, HID, HID, HID, HID,
        nullptr, S2t, KP, 0);

    // x2 partials = adj @ S2   (M=NROW, Nn=NCLS, K=KP, split-K=8, fp32-A)
    gemm_bt<64, true, 2><<<dim3(157, 1, KSPLIT4), 256, 0, stream>>>(
        adj, S2t, NROW, NCLS, KP, NROW, NROW, KP, KSPAN4,
        part, nullptr, NCLS, (long)NROW * NCLS);

    // reduce + b2 + log_softmax -> second output
    logsoftmax_fin<<<2500, 256, 0, stream>>>(part, b2, out + (long)NROW * HID, NROW);
}